// Round 11
// baseline (227.414 us; speedup 1.0000x reference)
//
#include <hip/hip_runtime.h>
#include <hip/hip_bf16.h>
#include <hip/hip_fp16.h>

// Sizes (fixed by the problem)
#define Bsz 8
#define Nn 1024
#define Ss 64
#define Hh 32

typedef _Float16 half8 __attribute__((ext_vector_type(8)));
typedef _Float16 half4 __attribute__((ext_vector_type(4)));
typedef float f32x4 __attribute__((ext_vector_type(4)));

__device__ __forceinline__ void gload_lds16(const _Float16* g, _Float16* l) {
  __builtin_amdgcn_global_load_lds(
      (const __attribute__((address_space(1))) unsigned int*)g,
      (__attribute__((address_space(3))) unsigned int*)l, 16, 0, 0);
}

// ---------------------------------------------------------------------------
// Kernel 1 "prep" (merged): blocks [0,64): transpose x -> xT[b][t][m] fp16;
// blocks [64,72): Wu,Wc -> Wh[2][32][1024] fp16; blocks >=72: g -> gh fp16.
__global__ __launch_bounds__(256)
void prep(const float* __restrict__ x, const float* __restrict__ Wu,
          const float* __restrict__ Wc, const float* __restrict__ g,
          _Float16* __restrict__ xT, _Float16* __restrict__ Wh,
          _Float16* __restrict__ gh) {
  const int tid = threadIdx.x;
  if (blockIdx.x < 64) {
    // --- transpose: block (b, mtile): x[b][m0..m0+128][0..64] -> xT[b][t][m0..]
    const int b = blockIdx.x >> 3;
    const int m0 = (blockIdx.x & 7) * 128;
    __shared__ _Float16 tile[128 * 68];  // [m][t], stride 68 halves
    const int m = tid >> 1;
    const int hf = tid & 1;
    const float* src = x + ((size_t)(b * Nn + m0 + m)) * Ss + hf * 32;
#pragma unroll
    for (int i = 0; i < 8; ++i) {
      const float4 v = *(const float4*)(src + i * 4);
      half4 o;
      o[0] = (_Float16)v.x; o[1] = (_Float16)v.y;
      o[2] = (_Float16)v.z; o[3] = (_Float16)v.w;
      *(half4*)(&tile[m * 68 + hf * 32 + i * 4]) = o;
    }
    __syncthreads();
    const int t = tid & 63;
    const int q = tid >> 6;  // 0..3 -> m-chunk of 32
    _Float16* dst = xT + ((size_t)(b * 64 + t)) * Nn + m0 + q * 32;
#pragma unroll
    for (int i = 0; i < 4; ++i) {
      half8 o;
#pragma unroll
      for (int e = 0; e < 8; ++e) o[e] = tile[(q * 32 + i * 8 + e) * 68 + t];
      *(half8*)(dst + i * 8) = o;
    }
  } else if (blockIdx.x < 72) {
    // --- W convert: Wh flat [2*32*1024]: first Wu then Wc
    const int w = blockIdx.x - 64;
    const size_t i0 = ((size_t)(w * 256 + tid)) * 32;
#pragma unroll
    for (int i = 0; i < 8; ++i) {
      const size_t i4 = i0 + i * 4;
      const float* s = (i4 < 32768) ? (Wu + i4) : (Wc + (i4 - 32768));
      const float4 v = *(const float4*)s;
      half4 o;
      o[0] = (_Float16)v.x; o[1] = (_Float16)v.y;
      o[2] = (_Float16)v.z; o[3] = (_Float16)v.w;
      *(half4*)(&Wh[i4]) = o;
    }
  } else {
    // --- g convert
    const size_t i = ((size_t)(blockIdx.x - 72) * 256 + tid) * 4;
    const float4 v = *(const float4*)(&g[i]);
    half4 o;
    o[0] = (_Float16)v.x; o[1] = (_Float16)v.y;
    o[2] = (_Float16)v.z; o[3] = (_Float16)v.w;
    *(half4*)(&gh[i]) = o;
  }
}

// ---------------------------------------------------------------------------
// Kernel 2: fused GEMM + in-register GRU affine scan.
// Per (u,b): Y[r][n] = sum_k x[k][t] * (Wg[u][k]*g[n][k]), r = gate*64+t.
// W folded into the B-operand (bf per gate) -> 16 pk_mul/step (was 32).
// Double-buffered LDS, raw s_barrier pairs, counted vmcnt(3) (never 0 in-loop).
// W row pair preloaded to LDS so the K-loop's only VMEM = 3 stage gload_lds.
// Epilogue: 64-step GRU as in-register affine-map composition (R10, verified).
__global__ __launch_bounds__(256)
void gemm_recur(const _Float16* __restrict__ xT, const _Float16* __restrict__ Wh,
                const _Float16* __restrict__ G, const float* __restrict__ bu,
                const float* __restrict__ bc, const float* __restrict__ h0,
                float* __restrict__ H) {
  __shared__ __align__(16) char smem[28672];
  _Float16* X0 = (_Float16*)smem;             // [64][32]  4 KB
  _Float16* G0 = (_Float16*)(smem + 4096);    // [128][32] 8 KB
  _Float16* X1 = (_Float16*)(smem + 12288);   // 4 KB
  _Float16* G1 = (_Float16*)(smem + 16384);   // 8 KB
  _Float16* Ws = (_Float16*)(smem + 24576);   // [2][1024] 4 KB (W rows, u fixed)

  // XCD-chunked bijective remap (2048 blocks % 8 == 0): each XCD -> one b.
  const int id = blockIdx.x;
  const int wg = (id & 7) * 256 + (id >> 3);
  const int b = wg >> 8;
  const int u = wg & 31;
  const int col0 = ((wg >> 5) & 7) * 128;

  const int tid = threadIdx.x;
  const int lane = tid & 63;
  const int wave = tid >> 6;
  const int wc = wave * 32;  // wave's n-column offset within 128-tile
  const int l15 = lane & 15;
  const int s = lane >> 4;

  const _Float16* Xb = xT + (size_t)b * 64 * Nn;           // [t][m]
  const _Float16* Gb = G + ((size_t)b * Nn + col0) * Nn;   // [n][m]

  const int srow = lane >> 2;                             // staging row 0..15
  const int ssw = ((lane & 3) ^ ((lane >> 3) & 3)) * 8;   // swizzled SOURCE slot
  const int ps8 = (s ^ ((l15 >> 1) & 3)) * 8;             // swizzled READ slot

  f32x4 acc[8][2] = {};  // [mi: rows mi*16.. (mi<4 gate0, else gate1)][ni]

#define STAGE(k0s, Xd, Gd)                                                     \
  do {                                                                         \
    gload_lds16(Xb + (size_t)(wave * 16 + srow) * Nn + (k0s) + ssw,            \
                (Xd) + wave * 512);                                            \
    gload_lds16(Gb + (size_t)(wave * 32 + srow) * Nn + (k0s) + ssw,            \
                (Gd) + wave * 1024);                                           \
    gload_lds16(Gb + (size_t)(wave * 32 + 16 + srow) * Nn + (k0s) + ssw,       \
                (Gd) + wave * 1024 + 512);                                     \
  } while (0)

  // prologue: preload W rows (u, 32+u) to LDS + first tile; full drain once.
  gload_lds16(Wh + (size_t)(wave >> 1) * 32768 + (size_t)u * Nn +
                  ((wave & 1) * 512) + lane * 8,
              Ws + (wave >> 1) * 1024 + (wave & 1) * 512);
  STAGE(0, X0, G0);
  __syncthreads();

  const _Float16 *Xc = X0, *Gc = G0, *Xn = X1, *Gn = G1;
  for (int kk = 0; kk < 32; ++kk) {
    if (kk < 31) {
      STAGE((kk + 1) * 32, (_Float16*)Xn, (_Float16*)Gn);
      asm volatile("s_waitcnt vmcnt(3)" ::: "memory");
    } else {
      asm volatile("s_waitcnt vmcnt(0)" ::: "memory");
    }
    __builtin_amdgcn_sched_barrier(0);
    __builtin_amdgcn_s_barrier();      // all waves: current buffer staged
    __builtin_amdgcn_sched_barrier(0);

    const int k0 = kk * 32;
    const half8 wv0 = *(const half8*)(Ws + k0 + s * 8);
    const half8 wv1 = *(const half8*)(Ws + 1024 + k0 + s * 8);
    half8 xf[4], bf0[2], bf1[2];
#pragma unroll
    for (int q = 0; q < 4; ++q)
      xf[q] = *(const half8*)(&Xc[(q * 16 + l15) * 32 + ps8]);
#pragma unroll
    for (int ni = 0; ni < 2; ++ni) {
      const half8 gr = *(const half8*)(&Gc[(wc + ni * 16 + l15) * 32 + ps8]);
      bf0[ni] = gr * wv0;  // W folded into B-operand (per gate)
      bf1[ni] = gr * wv1;
    }
#pragma unroll
    for (int mi = 0; mi < 4; ++mi)
#pragma unroll
      for (int ni = 0; ni < 2; ++ni)
        acc[mi][ni] = __builtin_amdgcn_mfma_f32_16x16x32_f16(xf[mi], bf0[ni], acc[mi][ni], 0, 0, 0);
#pragma unroll
    for (int mi = 0; mi < 4; ++mi)
#pragma unroll
      for (int ni = 0; ni < 2; ++ni)
        acc[mi + 4][ni] = __builtin_amdgcn_mfma_f32_16x16x32_f16(xf[mi], bf1[ni], acc[mi + 4][ni], 0, 0, 0);

    __builtin_amdgcn_sched_barrier(0);
    __builtin_amdgcn_s_barrier();      // safe to overwrite current buffer
    const _Float16* tp;
    tp = Xc; Xc = Xn; Xn = tp;
    tp = Gc; Gc = Gn; Gn = tp;
  }
#undef STAGE

  // --- epilogue: in-register GRU affine scan (verified R10).
  // Lane (s,l15) holds, for col n=wc+ni*16+l15: rows r=mi*16+s*4+j.
  // gate0 y_u = acc[mi][ni][j], gate1 y_c = acc[mi+4][ni][j], t = mi*16+s*4+j.
  const float bias_u = bu[u];
  const float bias_c = bc[u];
#pragma unroll
  for (int ni = 0; ni < 2; ++ni) {
    float At = 1.f, Bt = 0.f;  // running composition over mi (t ascending)
#pragma unroll
    for (int mi = 0; mi < 4; ++mi) {
      // local compose over j: t = mi*16 + s*4 + j, ascending j
      float A = 1.f, B = 0.f;
#pragma unroll
      for (int j = 0; j < 4; ++j) {
        const float yu = acc[mi][ni][j] + bias_u;
        const float yc = acc[mi + 4][ni][j] + bias_c;
        const float ug = 1.f / (1.f + __expf(-yu));
        const float e = __expf(-2.f * fabsf(yc));
        float th = (1.f - e) / (1.f + e);
        th = yc < 0.f ? -th : th;
        const float bj = (1.f - ug) * th;
        B = ug * B + bj;  // h -> ug*h + bj applied after current map
        A = ug * A;
      }
      // cross-s fold (t-ascending): gather group s'=0..3 maps for this l15
      float Aall = __shfl(A, l15, 64);
      float Ball = __shfl(B, l15, 64);
#pragma unroll
      for (int sp = 1; sp < 4; ++sp) {
        const float As = __shfl(A, sp * 16 + l15, 64);
        const float Bs = __shfl(B, sp * 16 + l15, 64);
        Ball = As * Ball + Bs;
        Aall = As * Aall;
      }
      // fold this mi-block into the running total
      Bt = Aall * Bt + Ball;
      At = Aall * At;
    }
    // lane-group s == 2*ni writes (all s-groups hold identical totals)
    if (s == (ni << 1)) {
      const int n = col0 + wc + ni * 16 + l15;
      const float hv = At * h0[u * Nn + n] + Bt;
      H[((size_t)b * Hh + u) * Nn + n] = hv;
    }
  }
}

// ---------------------------------------------------------------------------
// Kernel 3: prediction head, thread per (b,n). 64 blocks x 128 threads.
__global__ __launch_bounds__(128)
void head(const float* __restrict__ H, const float* __restrict__ W1,
          const float* __restrict__ b1, const float* __restrict__ W2,
          const float* __restrict__ b2, const float* __restrict__ Wd,
          const float* __restrict__ bd, float* __restrict__ out) {
  const int b = blockIdx.x >> 3;
  const int n = (blockIdx.x & 7) * 128 + threadIdx.x;
  const float* Hb = H + (size_t)b * Hh * Nn;
  float h[32];
#pragma unroll
  for (int u = 0; u < 32; ++u) h[u] = Hb[u * Nn + n];
  float x1[32];
#pragma unroll 4
  for (int v = 0; v < 32; ++v) {
    float a = b1[v];
#pragma unroll
    for (int u = 0; u < 32; ++u) a += W1[v * 32 + u] * h[u];
    x1[v] = a > 0.f ? a : 0.01f * a;
  }
  float x2[32];
#pragma unroll 4
  for (int v = 0; v < 32; ++v) {
    float a = b2[v];
#pragma unroll
    for (int u = 0; u < 32; ++u) a += W2[v * 64 + u] * x1[u];
#pragma unroll
    for (int u = 0; u < 32; ++u) a += W2[v * 64 + 32 + u] * h[u];
    x2[v] = a > 0.f ? a : 0.01f * a;
  }
  float o = bd[n];
#pragma unroll
  for (int v = 0; v < 32; ++v) o += Wd[n * 64 + v] * x2[v];
#pragma unroll
  for (int v = 0; v < 32; ++v) o += Wd[n * 64 + 32 + v] * h[v];
  out[(size_t)b * Nn + n] = o;
}

// ---------------------------------------------------------------------------
extern "C" void kernel_launch(void* const* d_in, const int* in_sizes, int n_in,
                              void* d_out, int out_size, void* d_ws, size_t ws_size,
                              hipStream_t stream) {
  const float* x  = (const float*)d_in[0];
  // d_in[1] = mask (unused)
  const float* g  = (const float*)d_in[2];
  // d_in[3]/d_in[4] = Wf/bf (mathematically unused)
  const float* Wu = (const float*)d_in[5];
  const float* bu = (const float*)d_in[6];
  const float* Wc = (const float*)d_in[7];
  const float* bc = (const float*)d_in[8];
  const float* h0 = (const float*)d_in[9];
  const float* W1 = (const float*)d_in[10];
  const float* b1 = (const float*)d_in[11];
  const float* W2 = (const float*)d_in[12];
  const float* b2 = (const float*)d_in[13];
  const float* Wd = (const float*)d_in[14];
  const float* bd = (const float*)d_in[15];
  float* out = (float*)d_out;

  char* ws = (char*)d_ws;
  _Float16* xT = (_Float16*)(ws);                        // 8*64*1024*2 = 1 MB
  _Float16* Wh = (_Float16*)(ws + (size_t)(1u << 20));   // 128 KB
  _Float16* gh = (_Float16*)(ws + (size_t)(2u << 20));   // 16 MB
  float*    Hx = (float*)  (ws + (size_t)(18u << 20));   // 1 MB

  prep<<<72 + 8192, 256, 0, stream>>>(x, Wu, Wc, g, xT, Wh, gh);
  gemm_recur<<<2048, 256, 0, stream>>>(xT, Wh, gh, bu, bc, h0, Hx);
  head<<<64, 128, 0, stream>>>(Hx, W1, b1, W2, b2, Wd, bd, out);
}

// Round 12
// 220.272 us; speedup vs baseline: 1.0324x; 1.0324x over previous
//
#include <hip/hip_runtime.h>
#include <hip/hip_bf16.h>
#include <hip/hip_fp16.h>

// Sizes (fixed by the problem)
#define Bsz 8
#define Nn 1024
#define Ss 64
#define Hh 32

typedef _Float16 half8 __attribute__((ext_vector_type(8)));
typedef _Float16 half4 __attribute__((ext_vector_type(4)));
typedef float f32x4 __attribute__((ext_vector_type(4)));

__device__ __forceinline__ void gload_lds16(const _Float16* g, _Float16* l) {
  __builtin_amdgcn_global_load_lds(
      (const __attribute__((address_space(1))) unsigned int*)g,
      (__attribute__((address_space(3))) unsigned int*)l, 16, 0, 0);
}

// ---------------------------------------------------------------------------
// Kernel 1 "prep" (merged): blocks [0,64): transpose x -> xT[b][t][m] fp16;
// blocks [64,72): Wu,Wc -> Wh[2][32][1024] fp16; blocks >=72: g -> gh fp16.
__global__ __launch_bounds__(256)
void prep(const float* __restrict__ x, const float* __restrict__ Wu,
          const float* __restrict__ Wc, const float* __restrict__ g,
          _Float16* __restrict__ xT, _Float16* __restrict__ Wh,
          _Float16* __restrict__ gh) {
  const int tid = threadIdx.x;
  if (blockIdx.x < 64) {
    // --- transpose: block (b, mtile): x[b][m0..m0+128][0..64] -> xT[b][t][m0..]
    const int b = blockIdx.x >> 3;
    const int m0 = (blockIdx.x & 7) * 128;
    __shared__ _Float16 tile[128 * 68];  // [m][t], stride 68 halves
    const int m = tid >> 1;
    const int hf = tid & 1;
    const float* src = x + ((size_t)(b * Nn + m0 + m)) * Ss + hf * 32;
#pragma unroll
    for (int i = 0; i < 8; ++i) {
      const float4 v = *(const float4*)(src + i * 4);
      half4 o;
      o[0] = (_Float16)v.x; o[1] = (_Float16)v.y;
      o[2] = (_Float16)v.z; o[3] = (_Float16)v.w;
      *(half4*)(&tile[m * 68 + hf * 32 + i * 4]) = o;
    }
    __syncthreads();
    const int t = tid & 63;
    const int q = tid >> 6;  // 0..3 -> m-chunk of 32
    _Float16* dst = xT + ((size_t)(b * 64 + t)) * Nn + m0 + q * 32;
#pragma unroll
    for (int i = 0; i < 4; ++i) {
      half8 o;
#pragma unroll
      for (int e = 0; e < 8; ++e) o[e] = tile[(q * 32 + i * 8 + e) * 68 + t];
      *(half8*)(dst + i * 8) = o;
    }
  } else if (blockIdx.x < 72) {
    // --- W convert: Wh flat [2*32*1024]: first Wu then Wc
    const int w = blockIdx.x - 64;
    const size_t i0 = ((size_t)(w * 256 + tid)) * 32;
#pragma unroll
    for (int i = 0; i < 8; ++i) {
      const size_t i4 = i0 + i * 4;
      const float* s = (i4 < 32768) ? (Wu + i4) : (Wc + (i4 - 32768));
      const float4 v = *(const float4*)s;
      half4 o;
      o[0] = (_Float16)v.x; o[1] = (_Float16)v.y;
      o[2] = (_Float16)v.z; o[3] = (_Float16)v.w;
      *(half4*)(&Wh[i4]) = o;
    }
  } else {
    // --- g convert
    const size_t i = ((size_t)(blockIdx.x - 72) * 256 + tid) * 4;
    const float4 v = *(const float4*)(&g[i]);
    half4 o;
    o[0] = (_Float16)v.x; o[1] = (_Float16)v.y;
    o[2] = (_Float16)v.z; o[3] = (_Float16)v.w;
    *(half4*)(&gh[i]) = o;
  }
}

// ---------------------------------------------------------------------------
// Kernel 2: fused GEMM + in-register GRU affine scan.
// Per (u,b): Y[r][n] = sum_k Wg[u][k]*x[k][t]*g[n][k], r = gate*64+t.
// Block = 128(M) x 128(N), 4 waves each own ALL 128 M-rows x 32 N-cols.
// BK=64 as TWO BK=32 sub-tiles per barrier pair (R10 addressing verbatim):
// 16 barrier pairs total (was 32), 32 MFMA per pair, setprio around cluster.
// Epilogue: 64-step GRU as in-register affine-map composition (R10, verified).
__global__ __launch_bounds__(256)
void gemm_recur(const _Float16* __restrict__ xT, const _Float16* __restrict__ Wh,
                const _Float16* __restrict__ G, const float* __restrict__ bu,
                const float* __restrict__ bc, const float* __restrict__ h0,
                float* __restrict__ H) {
  __shared__ __align__(16) char smem[24576];
  _Float16* X0 = (_Float16*)smem;            // [64][32]  4 KB (t-rows, k lo)
  _Float16* G0 = (_Float16*)(smem + 4096);   // [128][32] 8 KB (n-rows, k lo)
  _Float16* X1 = (_Float16*)(smem + 12288);  // 4 KB (k hi)
  _Float16* G1 = (_Float16*)(smem + 16384);  // 8 KB (k hi)

  // XCD-chunked bijective remap (2048 blocks % 8 == 0): each XCD -> one b.
  const int id = blockIdx.x;
  const int wg = (id & 7) * 256 + (id >> 3);
  const int b = wg >> 8;
  const int u = wg & 31;
  const int col0 = ((wg >> 5) & 7) * 128;

  const int tid = threadIdx.x;
  const int lane = tid & 63;
  const int wave = tid >> 6;
  const int wc = wave * 32;  // wave's n-column offset within 128-tile
  const int l15 = lane & 15;
  const int s = lane >> 4;

  const _Float16* Xb = xT + (size_t)b * 64 * Nn;           // [t][m]
  const _Float16* Gb = G + ((size_t)b * Nn + col0) * Nn;   // [n][m]
  const _Float16* Wg0 = Wh + (size_t)u * Nn;               // gate0 (update)
  const _Float16* Wg1 = Wh + (size_t)(32 + u) * Nn;        // gate1 (cand)

  const int srow = lane >> 2;                             // staging row 0..15
  const int ssw = ((lane & 3) ^ ((lane >> 3) & 3)) * 8;   // swizzled SOURCE slot
  const int ps8 = (s ^ ((l15 >> 1) & 3)) * 8;             // swizzled READ slot

  f32x4 acc[8][2] = {};  // [mi: rows mi*16.. (mi<4 gate0, else gate1)][ni]

#define STAGE(k0s, Xd, Gd)                                                     \
  do {                                                                         \
    gload_lds16(Xb + (size_t)(wave * 16 + srow) * Nn + (k0s) + ssw,            \
                (Xd) + wave * 512);                                            \
    gload_lds16(Gb + (size_t)(wave * 32 + srow) * Nn + (k0s) + ssw,            \
                (Gd) + wave * 1024);                                           \
    gload_lds16(Gb + (size_t)(wave * 32 + 16 + srow) * Nn + (k0s) + ssw,       \
                (Gd) + wave * 1024 + 512);                                     \
  } while (0)

#define COMPUTE(k0c, Xd, Gd)                                                   \
  do {                                                                         \
    const half8 wv0 = *(const half8*)(Wg0 + (k0c) + s * 8);                    \
    const half8 wv1 = *(const half8*)(Wg1 + (k0c) + s * 8);                    \
    half8 xf[4], bf[2];                                                        \
    _Pragma("unroll") for (int q = 0; q < 4; ++q)                              \
        xf[q] = *(const half8*)(&(Xd)[(q * 16 + l15) * 32 + ps8]);             \
    _Pragma("unroll") for (int ni = 0; ni < 2; ++ni)                           \
        bf[ni] = *(const half8*)(&(Gd)[(wc + ni * 16 + l15) * 32 + ps8]);      \
    _Pragma("unroll") for (int mi = 0; mi < 8; ++mi) {                         \
      const half8 af = xf[mi & 3] * (mi < 4 ? wv0 : wv1);                      \
      _Pragma("unroll") for (int ni = 0; ni < 2; ++ni)                         \
          acc[mi][ni] = __builtin_amdgcn_mfma_f32_16x16x32_f16(                \
              af, bf[ni], acc[mi][ni], 0, 0, 0);                               \
    }                                                                          \
  } while (0)

  for (int kk = 0; kk < 16; ++kk) {
    const int k0 = kk * 64;
    STAGE(k0, X0, G0);
    STAGE(k0 + 32, X1, G1);
    __syncthreads();
    __builtin_amdgcn_s_setprio(1);
    COMPUTE(k0, X0, G0);
    COMPUTE(k0 + 32, X1, G1);
    __builtin_amdgcn_s_setprio(0);
    __syncthreads();
  }
#undef STAGE
#undef COMPUTE

  // --- epilogue: in-register GRU affine scan (verified R10).
  // Lane (s,l15) holds, for col n=wc+ni*16+l15: rows r=mi*16+s*4+j.
  // gate0 y_u = acc[mi][ni][j], gate1 y_c = acc[mi+4][ni][j], t = mi*16+s*4+j.
  const float bias_u = bu[u];
  const float bias_c = bc[u];
#pragma unroll
  for (int ni = 0; ni < 2; ++ni) {
    float At = 1.f, Bt = 0.f;  // running composition over mi (t ascending)
#pragma unroll
    for (int mi = 0; mi < 4; ++mi) {
      // local compose over j: t = mi*16 + s*4 + j, ascending j
      float A = 1.f, B = 0.f;
#pragma unroll
      for (int j = 0; j < 4; ++j) {
        const float yu = acc[mi][ni][j] + bias_u;
        const float yc = acc[mi + 4][ni][j] + bias_c;
        const float ug = 1.f / (1.f + __expf(-yu));
        const float e = __expf(-2.f * fabsf(yc));
        float th = (1.f - e) / (1.f + e);
        th = yc < 0.f ? -th : th;
        const float bj = (1.f - ug) * th;
        B = ug * B + bj;  // h -> ug*h + bj applied after current map
        A = ug * A;
      }
      // cross-s fold (t-ascending): gather group s'=0..3 maps for this l15
      float Aall = __shfl(A, l15, 64);
      float Ball = __shfl(B, l15, 64);
#pragma unroll
      for (int sp = 1; sp < 4; ++sp) {
        const float As = __shfl(A, sp * 16 + l15, 64);
        const float Bs = __shfl(B, sp * 16 + l15, 64);
        Ball = As * Ball + Bs;
        Aall = As * Aall;
      }
      // fold this mi-block into the running total
      Bt = Aall * Bt + Ball;
      At = Aall * At;
    }
    // lane-group s == 2*ni writes (all s-groups hold identical totals)
    if (s == (ni << 1)) {
      const int n = col0 + wc + ni * 16 + l15;
      const float hv = At * h0[u * Nn + n] + Bt;
      H[((size_t)b * Hh + u) * Nn + n] = hv;
    }
  }
}

// ---------------------------------------------------------------------------
// Kernel 3: prediction head, thread per (b,n). 64 blocks x 128 threads.
__global__ __launch_bounds__(128)
void head(const float* __restrict__ H, const float* __restrict__ W1,
          const float* __restrict__ b1, const float* __restrict__ W2,
          const float* __restrict__ b2, const float* __restrict__ Wd,
          const float* __restrict__ bd, float* __restrict__ out) {
  const int b = blockIdx.x >> 3;
  const int n = (blockIdx.x & 7) * 128 + threadIdx.x;
  const float* Hb = H + (size_t)b * Hh * Nn;
  float h[32];
#pragma unroll
  for (int u = 0; u < 32; ++u) h[u] = Hb[u * Nn + n];
  float x1[32];
#pragma unroll 4
  for (int v = 0; v < 32; ++v) {
    float a = b1[v];
#pragma unroll
    for (int u = 0; u < 32; ++u) a += W1[v * 32 + u] * h[u];
    x1[v] = a > 0.f ? a : 0.01f * a;
  }
  float x2[32];
#pragma unroll 4
  for (int v = 0; v < 32; ++v) {
    float a = b2[v];
#pragma unroll
    for (int u = 0; u < 32; ++u) a += W2[v * 64 + u] * x1[u];
#pragma unroll
    for (int u = 0; u < 32; ++u) a += W2[v * 64 + 32 + u] * h[u];
    x2[v] = a > 0.f ? a : 0.01f * a;
  }
  float o = bd[n];
#pragma unroll
  for (int v = 0; v < 32; ++v) o += Wd[n * 64 + v] * x2[v];
#pragma unroll
  for (int v = 0; v < 32; ++v) o += Wd[n * 64 + 32 + v] * h[v];
  out[(size_t)b * Nn + n] = o;
}

// ---------------------------------------------------------------------------
extern "C" void kernel_launch(void* const* d_in, const int* in_sizes, int n_in,
                              void* d_out, int out_size, void* d_ws, size_t ws_size,
                              hipStream_t stream) {
  const float* x  = (const float*)d_in[0];
  // d_in[1] = mask (unused)
  const float* g  = (const float*)d_in[2];
  // d_in[3]/d_in[4] = Wf/bf (mathematically unused)
  const float* Wu = (const float*)d_in[5];
  const float* bu = (const float*)d_in[6];
  const float* Wc = (const float*)d_in[7];
  const float* bc = (const float*)d_in[8];
  const float* h0 = (const float*)d_in[9];
  const float* W1 = (const float*)d_in[10];
  const float* b1 = (const float*)d_in[11];
  const float* W2 = (const float*)d_in[12];
  const float* b2 = (const float*)d_in[13];
  const float* Wd = (const float*)d_in[14];
  const float* bd = (const float*)d_in[15];
  float* out = (float*)d_out;

  char* ws = (char*)d_ws;
  _Float16* xT = (_Float16*)(ws);                        // 8*64*1024*2 = 1 MB
  _Float16* Wh = (_Float16*)(ws + (size_t)(1u << 20));   // 128 KB
  _Float16* gh = (_Float16*)(ws + (size_t)(2u << 20));   // 16 MB
  float*    Hx = (float*)  (ws + (size_t)(18u << 20));   // 1 MB

  prep<<<72 + 8192, 256, 0, stream>>>(x, Wu, Wc, g, xT, Wh, gh);
  gemm_recur<<<2048, 256, 0, stream>>>(xT, Wh, gh, bu, bc, h0, Hx);
  head<<<64, 128, 0, stream>>>(Hx, W1, b1, W2, b2, Wd, bd, out);
}